// Round 10
// baseline (67.343 us; speedup 1.0000x reference)
//
#include <hip/hip_runtime.h>

#define C_CH 64
#define NX 432
#define NY 496
#define NYQ 124                    // NY/4
#define PLANEQ (NX * NYQ)          // float4s per (b,c) plane = 53568
#define MPER_MAX 12032             // LDS slots for one sample's pillars (>=12000)

// ---------- fast path: memset(-1) + index scatter + staged plane writer ----------

// Scatter LOCAL pillar index j (= m - s*mper, sample-contiguous input) into
// map[s, NX-1-x, y] (flip pre-applied so the writer reads linearly).
__global__ void scatter_idx_kernel(const int* __restrict__ bidx,
                                   const int* __restrict__ sidx,
                                   int* __restrict__ map, int M, int mper) {
    int m = blockIdx.x * blockDim.x + threadIdx.x;
    if (m >= M) return;
    int y = bidx[3 * m + 1];
    int x = bidx[3 * m + 2];
    int s = sidx[m];
    map[(size_t)s * (NX * NY) + (size_t)(NX - 1 - x) * NY + y] = m - s * mper;
}

// Block = half of one (b,c) plane: 512 blocks (2/CU), 1024 threads.
// Phase A: stage ALL of sample b's channel-c values into LDS (47 KB) — feats
//   lines are L2/L3-shared across the 64 c-blocks of the sample.
// Phase B: monotone 428 KB contiguous store stream; data deps are only a
//   coalesced int4 map read (L2-resident, prefetched 1 iter ahead) + LDS
//   lookups. Structurally fill-like: long DRAM bursts, no scattered loads.
__global__ __launch_bounds__(1024) void plane_stage_kernel(
        const float* __restrict__ feats,
        const int4* __restrict__ map4,
        float4* __restrict__ out, int mper) {
    __shared__ float svals[MPER_MAX];

    const int blk   = blockIdx.x;
    const int plane = blk >> 1;             // b*C_CH + c
    const int half  = blk & 1;
    const int b = plane >> 6;
    const int c = plane & (C_CH - 1);

    // Phase A: svals[j] = feats[(b*mper + j)*64 + c]
    const size_t fbase = (size_t)b * mper * C_CH + c;
    for (int j = threadIdx.x; j < mper; j += 1024)
        svals[j] = feats[fbase + (size_t)j * C_CH];
    __syncthreads();

    // Phase B: write half a plane, monotone.
    const int HQ = PLANEQ / 2;              // 26784
    const int q0 = half * HQ;
    const int4* mp = map4 + (size_t)b * PLANEQ + q0;
    float4* ob = out + (size_t)plane * PLANEQ + q0;

    int q = threadIdx.x;
    int4 mm = (q < HQ) ? mp[q] : make_int4(-1, -1, -1, -1);
    while (q < HQ) {
        int qn = q + 1024;
        int4 mn = (qn < HQ) ? mp[qn] : make_int4(-1, -1, -1, -1);
        float4 v = make_float4(0.f, 0.f, 0.f, 0.f);
        if (mm.x >= 0) v.x = svals[mm.x];
        if (mm.y >= 0) v.y = svals[mm.y];
        if (mm.z >= 0) v.z = svals[mm.z];
        if (mm.w >= 0) v.w = svals[mm.w];
        ob[q] = v;
        q = qn; mm = mn;
    }
}

// ---------- fallback path (if d_ws too small): zero + direct scatter ----------

__global__ void zero_out_kernel(float4* __restrict__ out, int nq) {
    int i = blockIdx.x * blockDim.x + threadIdx.x;
    if (i < nq) out[i] = make_float4(0.f, 0.f, 0.f, 0.f);
}

__global__ void scatter_feats_kernel(const float* __restrict__ feats,
                                     const int* __restrict__ bidx,
                                     const int* __restrict__ sidx,
                                     float* __restrict__ out, int M) {
    int tid = blockIdx.x * blockDim.x + threadIdx.x;
    if (tid >= M * C_CH) return;
    int m = tid >> 6;
    int c = tid & (C_CH - 1);
    int y = bidx[3 * m + 1];
    int x = bidx[3 * m + 2];
    int s = sidx[m];
    size_t o = (((size_t)s * C_CH + c) * NX + (NX - 1 - x)) * NY + y;
    out[o] = feats[tid];
}

extern "C" void kernel_launch(void* const* d_in, const int* in_sizes, int n_in,
                              void* d_out, int out_size, void* d_ws, size_t ws_size,
                              hipStream_t stream) {
    const float* feats = (const float*)d_in[0];
    const int*   bidx  = (const int*)d_in[1];
    const int*   sidx  = (const int*)d_in[2];
    float*       out   = (float*)d_out;

    const int M = in_sizes[0] / C_CH;               // 48000 pillars total
    const int B = out_size / (C_CH * NX * NY);      // 4
    const int mper = M / B;                         // 12000 (sample-contiguous)

    const size_t map_elems = (size_t)B * NX * NY;   // 857,088
    const size_t map_bytes = map_elems * sizeof(int);

    if (ws_size >= map_bytes && mper <= MPER_MAX) {
        int* map = (int*)d_ws;
        hipMemsetAsync(map, 0xFF, map_bytes, stream);   // -1 fill
        scatter_idx_kernel<<<(M + 255) / 256, 256, 0, stream>>>(bidx, sidx, map, M, mper);
        plane_stage_kernel<<<B * C_CH * 2, 1024, 0, stream>>>(
            feats, (const int4*)map, (float4*)out, mper);
    } else {
        int nq = out_size / 4;
        zero_out_kernel<<<(nq + 255) / 256, 256, 0, stream>>>((float4*)out, nq);
        int nt = M * C_CH;
        scatter_feats_kernel<<<(nt + 255) / 256, 256, 0, stream>>>(
            feats, bidx, sidx, out, M);
    }
}

// Round 11
// 49.550 us; speedup vs baseline: 1.3591x; 1.3591x over previous
//
#include <hip/hip_runtime.h>

#define C_CH 64
#define NX 432
#define NY 496
#define NYQ 124                    // NY/4
#define PLANEQ (NX * NYQ)          // float4s per (b,c) plane = 53568
#define SLOTS 96                   // staged pillars/column (expected ~28)
#define NXCD 8

// ---------- fast path: memset(-1) + index scatter + LDS-staged column writer ----------

// Scatter pillar index m into map[s, NX-1-x, y] (flip pre-applied so the
// writer reads its column slice contiguously).
__global__ void scatter_idx_kernel(const int* __restrict__ bidx,
                                   const int* __restrict__ sidx,
                                   int* __restrict__ map, int M) {
    int m = blockIdx.x * blockDim.x + threadIdx.x;
    if (m >= M) return;
    int y = bidx[3 * m + 1];
    int x = bidx[3 * m + 2];
    int s = sidx[m];
    map[(size_t)s * (NX * NY) + (size_t)(NX - 1 - x) * NY + y] = m;
}

// One block per (b, xo) column, XCD-swizzled: blocks land on XCDs in
// contiguous 216-column chunks, so each per-XCD L2 accumulates dirty write
// lines over contiguous 428KB spans per c-plane instead of 1984B fragments
// interleaved 8-ways -> better HBM eviction locality (T1).
// Stores are fed ONLY from LDS — no global-load dependency in the store loop.
__global__ __launch_bounds__(256) void column_write_kernel(
        const float* __restrict__ feats,
        const int* __restrict__ map,
        float4* __restrict__ out, int nwg) {
    __shared__ int4  map4[NYQ];             // slot (>=0), -1 empty, <=-2 direct
    __shared__ int   slot_m[SLOTS];
    __shared__ float rows[SLOTS][C_CH + 1]; // +1 pad: bank = (s + c) % 32
    __shared__ int   cnt;

    int* map_row = (int*)map4;
    // XCD-aware swizzle (bijective: nwg % 8 == 0 guaranteed by launcher)
    const int chunk = nwg / NXCD;
    const int blk = (blockIdx.x % NXCD) * chunk + blockIdx.x / NXCD;
    const int b   = blk / NX;
    const int xo  = blk - b * NX;
    const int tid = threadIdx.x;

    if (tid == 0) cnt = 0;
    __syncthreads();

    // Phase A: read column map slice (contiguous 496 ints), compact into slots
    const int* mp = map + ((size_t)b * NX + xo) * NY;
    for (int y = tid; y < NY; y += 256) {
        int m = mp[y];
        int v = -1;
        if (m >= 0) {
            int s = atomicAdd(&cnt, 1);
            if (s < SLOTS) { slot_m[s] = m; v = s; }
            else v = -2 - m;                // overflow: direct gather in phase C
        }
        map_row[y] = v;
    }
    __syncthreads();

    // Phase B: coalesced fetch of occupied pillar rows (256 B each) into LDS
    const int n = (cnt < SLOTS) ? cnt : SLOTS;
    for (int e = tid; e < n * C_CH; e += 256) {
        int s = e >> 6;
        int c = e & (C_CH - 1);
        rows[s][c] = feats[(size_t)slot_m[s] * C_CH + c];
    }
    __syncthreads();

    // Phase C: stream the (C=64, NYQ=124) slice. 128-thread group per c-plane
    // row -> 124 consecutive float4 stores (1984 B contiguous). Map quad is
    // loop-invariant per thread (hoisted). All loads are LDS.
    const int t    = tid & 127;             // yq
    const int cof  = tid >> 7;              // 0/1
    int4 mm = make_int4(-1, -1, -1, -1);
    if (t < NYQ) mm = map4[t];
    float4* ob = out + ((size_t)b * C_CH * NX + xo) * NYQ + t;

    #pragma unroll 4
    for (int c2 = 0; c2 < C_CH / 2; ++c2) {
        int c = (c2 << 1) + cof;
        if (t < NYQ) {
            float4 v = make_float4(0.f, 0.f, 0.f, 0.f);
            if (mm.x >= 0) v.x = rows[mm.x][c];
            else if (mm.x < -1) v.x = feats[(size_t)(-2 - mm.x) * C_CH + c];
            if (mm.y >= 0) v.y = rows[mm.y][c];
            else if (mm.y < -1) v.y = feats[(size_t)(-2 - mm.y) * C_CH + c];
            if (mm.z >= 0) v.z = rows[mm.z][c];
            else if (mm.z < -1) v.z = feats[(size_t)(-2 - mm.z) * C_CH + c];
            if (mm.w >= 0) v.w = rows[mm.w][c];
            else if (mm.w < -1) v.w = feats[(size_t)(-2 - mm.w) * C_CH + c];
            ob[(size_t)c * PLANEQ] = v;
        }
    }
}

// ---------- fallback path (if d_ws too small): zero + direct scatter ----------

__global__ void zero_out_kernel(float4* __restrict__ out, int nq) {
    int i = blockIdx.x * blockDim.x + threadIdx.x;
    if (i < nq) out[i] = make_float4(0.f, 0.f, 0.f, 0.f);
}

__global__ void scatter_feats_kernel(const float* __restrict__ feats,
                                     const int* __restrict__ bidx,
                                     const int* __restrict__ sidx,
                                     float* __restrict__ out, int M) {
    int tid = blockIdx.x * blockDim.x + threadIdx.x;
    if (tid >= M * C_CH) return;
    int m = tid >> 6;
    int c = tid & (C_CH - 1);
    int y = bidx[3 * m + 1];
    int x = bidx[3 * m + 2];
    int s = sidx[m];
    size_t o = (((size_t)s * C_CH + c) * NX + (NX - 1 - x)) * NY + y;
    out[o] = feats[tid];
}

extern "C" void kernel_launch(void* const* d_in, const int* in_sizes, int n_in,
                              void* d_out, int out_size, void* d_ws, size_t ws_size,
                              hipStream_t stream) {
    const float* feats = (const float*)d_in[0];
    const int*   bidx  = (const int*)d_in[1];
    const int*   sidx  = (const int*)d_in[2];
    float*       out   = (float*)d_out;

    const int M = in_sizes[0] / C_CH;               // 48000 pillars total
    const int B = out_size / (C_CH * NX * NY);      // 4

    const size_t map_elems = (size_t)B * NX * NY;   // 857,088
    const size_t map_bytes = map_elems * sizeof(int);
    const int nwg = B * NX;                         // 1728, divisible by 8

    if (ws_size >= map_bytes && (nwg % NXCD) == 0) {
        int* map = (int*)d_ws;
        hipMemsetAsync(map, 0xFF, map_bytes, stream);   // -1 fill
        scatter_idx_kernel<<<(M + 255) / 256, 256, 0, stream>>>(bidx, sidx, map, M);
        column_write_kernel<<<nwg, 256, 0, stream>>>(
            feats, map, (float4*)out, nwg);
    } else {
        int nq = out_size / 4;
        zero_out_kernel<<<(nq + 255) / 256, 256, 0, stream>>>((float4*)out, nq);
        int nt = M * C_CH;
        scatter_feats_kernel<<<(nt + 255) / 256, 256, 0, stream>>>(
            feats, bidx, sidx, out, M);
    }
}

// Round 12
// 44.894 us; speedup vs baseline: 1.5001x; 1.1037x over previous
//
#include <hip/hip_runtime.h>

#define C_CH 64
#define NX 432
#define NY 496
#define NYQ 124                    // NY/4
#define PLANEQ (NX * NYQ)          // float4s per (b,c) plane = 53568
#define SLOTS 64                   // staged pillars/column (mean 27.8, 64 ≈ 7 sigma; overflow correct via slow path)
#define NXCD 8

// ---------- fast path: memset(-1) + index scatter + LDS-staged column writer ----------

// Scatter pillar index m into map[s, NX-1-x, y] (flip pre-applied so the
// writer reads its column slice contiguously).
__global__ void scatter_idx_kernel(const int* __restrict__ bidx,
                                   const int* __restrict__ sidx,
                                   int* __restrict__ map, int M) {
    int m = blockIdx.x * blockDim.x + threadIdx.x;
    if (m >= M) return;
    int y = bidx[3 * m + 1];
    int x = bidx[3 * m + 2];
    int s = sidx[m];
    map[(size_t)s * (NX * NY) + (size_t)(NX - 1 - x) * NY + y] = m;
}

// One block per (b, xo) column. ~19 KB LDS -> 8 blocks/CU (thread cap), so
// each block's serial A->B prologue hides under 7 neighbors' store streams.
// Phase C fast path is BRANCHLESS: empty sites point at a dummy zero row, so
// every quad is 4 unconditional LDS reads + 1 coalesced float4 store.
__global__ __launch_bounds__(256) void column_write_kernel(
        const float* __restrict__ feats,
        const int* __restrict__ map,
        float4* __restrict__ out, int nwg) {
    __shared__ int4  map4[NYQ];              // slot in [0,SLOTS] (SLOTS = zero row), <=-2 direct
    __shared__ int   slot_m[SLOTS];
    __shared__ float rows[SLOTS + 1][C_CH + 1]; // +1 pad: bank = (s + c) % 32
    __shared__ int   cnt, ovf;

    int* map_row = (int*)map4;
    const int chunk = nwg / NXCD;            // bijective: launcher guarantees nwg % 8 == 0
    const int blk = (blockIdx.x % NXCD) * chunk + blockIdx.x / NXCD;
    const int b   = blk / NX;
    const int xo  = blk - b * NX;
    const int tid = threadIdx.x;

    if (tid == 0) { cnt = 0; ovf = 0; }
    if (tid < C_CH) rows[SLOTS][tid] = 0.0f; // dummy zero row for empty sites
    __syncthreads();

    // Phase A: read column map slice (contiguous 496 ints), compact into slots
    const int* mp = map + ((size_t)b * NX + xo) * NY;
    for (int y = tid; y < NY; y += 256) {
        int m = mp[y];
        int v = SLOTS;                       // empty -> zero row
        if (m >= 0) {
            int s = atomicAdd(&cnt, 1);
            if (s < SLOTS) { slot_m[s] = m; v = s; }
            else { v = -2 - m; ovf = 1; }    // overflow: direct gather in phase C
        }
        map_row[y] = v;
    }
    __syncthreads();

    // Phase B: coalesced fetch of occupied pillar rows (256 B each) into LDS
    const int n = (cnt < SLOTS) ? cnt : SLOTS;
    for (int e = tid; e < n * C_CH; e += 256) {
        int s = e >> 6;
        int c = e & (C_CH - 1);
        rows[s][c] = feats[(size_t)slot_m[s] * C_CH + c];
    }
    __syncthreads();

    // Phase C: stream the (C=64, NYQ=124) slice. 128-thread group per c-plane
    // row -> 124 consecutive float4 stores (1984 B contiguous). All loads LDS.
    const int t    = tid & 127;              // yq
    const int cof  = tid >> 7;               // 0/1
    int4 mm = make_int4(SLOTS, SLOTS, SLOTS, SLOTS);
    if (t < NYQ) mm = map4[t];
    float4* ob = out + ((size_t)b * C_CH * NX + xo) * NYQ + t;

    if (!ovf) {                              // block-uniform: the always-taken path
        #pragma unroll 8
        for (int c2 = 0; c2 < C_CH / 2; ++c2) {
            int c = (c2 << 1) + cof;
            if (t < NYQ) {
                float4 v;
                v.x = rows[mm.x][c];
                v.y = rows[mm.y][c];
                v.z = rows[mm.z][c];
                v.w = rows[mm.w][c];
                ob[(size_t)c * PLANEQ] = v;
            }
        }
    } else {                                 // correct slow path (never in practice)
        for (int c2 = 0; c2 < C_CH / 2; ++c2) {
            int c = (c2 << 1) + cof;
            if (t < NYQ) {
                float4 v;
                v.x = (mm.x >= 0) ? rows[mm.x][c] : feats[(size_t)(-2 - mm.x) * C_CH + c];
                v.y = (mm.y >= 0) ? rows[mm.y][c] : feats[(size_t)(-2 - mm.y) * C_CH + c];
                v.z = (mm.z >= 0) ? rows[mm.z][c] : feats[(size_t)(-2 - mm.z) * C_CH + c];
                v.w = (mm.w >= 0) ? rows[mm.w][c] : feats[(size_t)(-2 - mm.w) * C_CH + c];
                ob[(size_t)c * PLANEQ] = v;
            }
        }
    }
}

// ---------- fallback path (if d_ws too small): zero + direct scatter ----------

__global__ void zero_out_kernel(float4* __restrict__ out, int nq) {
    int i = blockIdx.x * blockDim.x + threadIdx.x;
    if (i < nq) out[i] = make_float4(0.f, 0.f, 0.f, 0.f);
}

__global__ void scatter_feats_kernel(const float* __restrict__ feats,
                                     const int* __restrict__ bidx,
                                     const int* __restrict__ sidx,
                                     float* __restrict__ out, int M) {
    int tid = blockIdx.x * blockDim.x + threadIdx.x;
    if (tid >= M * C_CH) return;
    int m = tid >> 6;
    int c = tid & (C_CH - 1);
    int y = bidx[3 * m + 1];
    int x = bidx[3 * m + 2];
    int s = sidx[m];
    size_t o = (((size_t)s * C_CH + c) * NX + (NX - 1 - x)) * NY + y;
    out[o] = feats[tid];
}

extern "C" void kernel_launch(void* const* d_in, const int* in_sizes, int n_in,
                              void* d_out, int out_size, void* d_ws, size_t ws_size,
                              hipStream_t stream) {
    const float* feats = (const float*)d_in[0];
    const int*   bidx  = (const int*)d_in[1];
    const int*   sidx  = (const int*)d_in[2];
    float*       out   = (float*)d_out;

    const int M = in_sizes[0] / C_CH;               // 48000 pillars total
    const int B = out_size / (C_CH * NX * NY);      // 4

    const size_t map_elems = (size_t)B * NX * NY;   // 857,088
    const size_t map_bytes = map_elems * sizeof(int);
    const int nwg = B * NX;                         // 1728, divisible by 8

    if (ws_size >= map_bytes && (nwg % NXCD) == 0) {
        int* map = (int*)d_ws;
        hipMemsetAsync(map, 0xFF, map_bytes, stream);   // -1 fill
        scatter_idx_kernel<<<(M + 255) / 256, 256, 0, stream>>>(bidx, sidx, map, M);
        column_write_kernel<<<nwg, 256, 0, stream>>>(
            feats, map, (float4*)out, nwg);
    } else {
        int nq = out_size / 4;
        zero_out_kernel<<<(nq + 255) / 256, 256, 0, stream>>>((float4*)out, nq);
        int nt = M * C_CH;
        scatter_feats_kernel<<<(nt + 255) / 256, 256, 0, stream>>>(
            feats, bidx, sidx, out, M);
    }
}